// Round 6
// baseline (200.086 us; speedup 1.0000x reference)
//
#include <hip/hip_runtime.h>
#include <hip/hip_bf16.h>

// ProjectionAggregating: B=4096, N=64, D=128
// out[b,d] = query_emb + final_refer / (1e-9 + ref_norm/query_norm*2.5)
// final_refer[b,d] = sum_n (h1@W2^T + b2)[b,n,d] * (refer_embs - start_embs*refer_r)[b,n,d]
// h1 = relu(query_r@W1a^T + refer_r@W1b^T + b1)   (W1a = W1[:, :128], W1b = W1[:, 128:])

typedef __attribute__((ext_vector_type(8))) short bf16x8;   // 8 bf16 = 4 VGPRs (MFMA A/B frag)
typedef __attribute__((ext_vector_type(4))) float f32x4;    // MFMA C/D frag

__device__ __forceinline__ unsigned short f2bf(float x) {
    unsigned int u = __float_as_uint(x);
    u += 0x7FFFu + ((u >> 16) & 1u);   // round-to-nearest-even
    return (unsigned short)(u >> 16);
}
__device__ __forceinline__ float bf2f(unsigned short h) {
    return __uint_as_float(((unsigned int)h) << 16);
}

// ---- kernel 1: convert W1b (W1[:,128:256]) and W2 to bf16 into workspace ----
__global__ __launch_bounds__(256) void pa_prep(const float* __restrict__ W1,
                                               const float* __restrict__ W2,
                                               unsigned short* __restrict__ w1b,
                                               unsigned short* __restrict__ w2b) {
    int i = blockIdx.x * 256 + threadIdx.x;   // grid covers 32768
    if (i < 16384) {
        int d = i >> 7, k = i & 127;
        w1b[i] = f2bf(W1[d * 256 + 128 + k]);
    } else {
        int j = i - 16384;
        w2b[j] = f2bf(W2[j]);
    }
}

// ---- kernel 2: qv[b,d] = b1[d] + sum_k query_r[b,k] * W1[d,k]  (f32, exact) ----
__global__ __launch_bounds__(256) void pa_qv(const float* __restrict__ query_r,
                                             const float* __restrict__ W1,
                                             const float* __restrict__ b1,
                                             float* __restrict__ qv) {
    __shared__ float wa[128][129];   // W1a, padded (+1) to break bank aliasing
    __shared__ float sq[32][128];    // 32 rows of query_r
    const int tid = threadIdx.x;
    const int b0 = blockIdx.x * 32;  // grid = 128 blocks

    for (int i = tid; i < 128 * 128; i += 256) {
        int d = i >> 7, k = i & 127;
        wa[d][k] = W1[d * 256 + k];
    }
    for (int i = tid; i < 32 * 128; i += 256) {
        sq[i >> 7][i & 127] = query_r[(size_t)b0 * 128 + i];
    }
    __syncthreads();

    const int d = tid & 127;
    const int rb = (tid >> 7) * 16;
    const float bb = b1[d];
    for (int j = 0; j < 16; ++j) {
        int r = rb + j;
        float a0 = 0.f, a1 = 0.f, a2 = 0.f, a3 = 0.f;  // 4-way ILP split
        #pragma unroll
        for (int k = 0; k < 128; k += 4) {
            a0 += sq[r][k + 0] * wa[d][k + 0];
            a1 += sq[r][k + 1] * wa[d][k + 1];
            a2 += sq[r][k + 2] * wa[d][k + 2];
            a3 += sq[r][k + 3] * wa[d][k + 3];
        }
        qv[(size_t)(b0 + r) * 128 + d] = bb + ((a0 + a1) + (a2 + a3));
    }
}

// ---- kernel 3: persistent grid-stride main kernel ----
// 1024 blocks (exactly 4/CU), each processes 4 b's (b = bid + i*1024).
// Per-iteration phase/barrier structure is IDENTICAL to the R4 kernel that
// passed replay validation. The only cross-iteration addition: next b's
// refer_r burst is issued after B4 (rburst regs are dead there), covered by
// gather + final + loop-back. R5's deep cross-barrier convoy is reverted.
__global__ __launch_bounds__(256, 4) void pa_main(
    const float* __restrict__ query_emb,
    const float* __restrict__ refer_embs,
    const float* __restrict__ refer_r,
    const float* __restrict__ start_embs,
    const float* __restrict__ qv,
    const unsigned short* __restrict__ w1b,
    const unsigned short* __restrict__ w2b,
    const float* __restrict__ b2,
    float* __restrict__ out) {
    __shared__ __align__(16) unsigned short sR[64 * 128];  // refer_r bf16 swz (16 KB), persists to gather
    __shared__ __align__(16) unsigned short sH[64 * 128];  // h1 bf16 swz -> attn bf16 (16 KB)
    __shared__ float sPart[8][132];                        // col-partials, padded (4.2 KB)
    __shared__ float sQv[128];
    __shared__ float sRed[4];

    const int bid  = blockIdx.x;     // 0..1023
    const int tid  = threadIdx.x;
    const int lane = tid & 63;
    const int wv   = tid >> 6;       // 4 waves; wave wv owns output cols [32*wv, 32*wv+32)
    const int hl   = lane & 15;
    const int qh   = lane >> 4;      // quarter-wave index
    const int wcol = wv * 32;

    // ---- prologue: first b's refer_r burst ----
    float4 rburst[8];
    {
        const float4* rr4 = (const float4*)(refer_r + (size_t)bid * 8192);
        #pragma unroll
        for (int it = 0; it < 8; ++it) rburst[it] = rr4[tid + it * 256];
    }

    #pragma unroll 1
    for (int i = 0; i < 4; ++i) {
        const int b = bid + i * 1024;
        const size_t base = (size_t)b * 8192;
        const float4* re4 = (const float4*)(refer_embs + base);
        const float4* se4 = (const float4*)(start_embs + base);

        // ---- stage: rburst -> sR (bf16, XOR-swizzled); small per-b loads ----
        float qvv = (tid < 128) ? qv[(size_t)b * 128 + tid] : 0.f;
        float qe  = (tid < 128) ? query_emb[(size_t)b * 128 + tid] : 0.f;
        bf16x8 bW[2][4];
        #pragma unroll
        for (int ct = 0; ct < 2; ++ct)
            #pragma unroll
            for (int ks = 0; ks < 4; ++ks)
                bW[ct][ks] = *(const bf16x8*)(w1b + (wcol + ct * 16 + hl) * 128 + ks * 32 + qh * 8);

        if (tid < 128) sQv[tid] = qvv;
        #pragma unroll
        for (int it = 0; it < 8; ++it) {
            int e0  = (tid + it * 256) * 4;
            int row = e0 >> 7;           // = it*8 + (tid>>5)
            int kc  = e0 & 127;          // = (tid&31)*4
            float4 r = rburst[it];
            ushort4 bv;
            bv.x = f2bf(r.x); bv.y = f2bf(r.y); bv.z = f2bf(r.z); bv.w = f2bf(r.w);
            int byte = row * 256 + ((kc * 2) ^ ((row & 7) << 4));
            *(ushort4*)((char*)sR + byte) = bv;
        }
        __syncthreads();   // B1: refer_r staged

        // ---- GEMM1: h1_part[row,col] = sum_k refer_r[row,k] * W1b[col,k] ----
        f32x4 acc1[4][2] = {};
        #pragma unroll
        for (int rt = 0; rt < 4; ++rt) {
            const int row = rt * 16 + hl;
            const int rsw = (row & 7) << 4;
            bf16x8 af[4];
            #pragma unroll
            for (int ks = 0; ks < 4; ++ks) {
                int byte = row * 256 + ((ks * 64 + qh * 16) ^ rsw);
                af[ks] = *(const bf16x8*)((const char*)sR + byte);
            }
            #pragma unroll
            for (int ct = 0; ct < 2; ++ct)
                #pragma unroll
                for (int ks = 0; ks < 4; ++ks)
                    acc1[rt][ct] = __builtin_amdgcn_mfma_f32_16x16x32_bf16(af[ks], bW[ct][ks], acc1[rt][ct], 0, 0, 0);
        }

        // ---- epilogue 1: h1 = relu(acc + qv[col]) -> sH ----
        // C/D layout: col = lane&15, row = (lane>>4)*4 + reg
        #pragma unroll
        for (int ct = 0; ct < 2; ++ct) {
            const int col = wcol + ct * 16 + hl;
            const float q = sQv[col];
            #pragma unroll
            for (int rt = 0; rt < 4; ++rt) {
                #pragma unroll
                for (int j = 0; j < 4; ++j) {
                    int row = rt * 16 + qh * 4 + j;
                    float h = acc1[rt][ct][j] + q;
                    h = h > 0.0f ? h : 0.0f;
                    int byte = row * 256 + ((col * 2) ^ ((row & 7) << 4));
                    *(unsigned short*)((char*)sH + byte) = f2bf(h);
                }
            }
        }
        __syncthreads();   // B2: h1 ready

        // ---- GEMM2: attn[row,col] = sum_k h1[row,k] * W2[col,k] ----
        bf16x8 bW2[2][4];
        #pragma unroll
        for (int ct = 0; ct < 2; ++ct)
            #pragma unroll
            for (int ks = 0; ks < 4; ++ks)
                bW2[ct][ks] = *(const bf16x8*)(w2b + (wcol + ct * 16 + hl) * 128 + ks * 32 + qh * 8);

        f32x4 acc2[4][2] = {};
        #pragma unroll
        for (int rt = 0; rt < 4; ++rt) {
            const int row = rt * 16 + hl;
            const int rsw = (row & 7) << 4;
            bf16x8 af[4];
            #pragma unroll
            for (int ks = 0; ks < 4; ++ks) {
                int byte = row * 256 + ((ks * 64 + qh * 16) ^ rsw);
                af[ks] = *(const bf16x8*)((const char*)sH + byte);
            }
            #pragma unroll
            for (int ct = 0; ct < 2; ++ct)
                #pragma unroll
                for (int ks = 0; ks < 4; ++ks)
                    acc2[rt][ct] = __builtin_amdgcn_mfma_f32_16x16x32_bf16(af[ks], bW2[ct][ks], acc2[rt][ct], 0, 0, 0);
        }

        // ---- issue first half of e/s stream (covered by epi2 + B3/B4) ----
        float4 ge[4], gs[4];
        #pragma unroll
        for (int j = 0; j < 4; ++j) {
            int idx = tid + j * 256;
            ge[j] = re4[idx];
            gs[j] = se4[idx];
        }
        __syncthreads();   // B3: all GEMM2 reads of sH done

        // ---- epilogue 2: attn(+b2) -> sH (same swizzle) ----
        #pragma unroll
        for (int ct = 0; ct < 2; ++ct) {
            const int col = wcol + ct * 16 + hl;
            const float bb = b2[col];
            #pragma unroll
            for (int rt = 0; rt < 4; ++rt) {
                #pragma unroll
                for (int j = 0; j < 4; ++j) {
                    int row = rt * 16 + qh * 4 + j;
                    int byte = row * 256 + ((col * 2) ^ ((row & 7) << 4));
                    *(unsigned short*)((char*)sH + byte) = f2bf(acc2[rt][ct][j] + bb);
                }
            }
        }
        __syncthreads();   // B4: attn ready

        // ---- prefetch next b's refer_r (rburst regs dead; cover = gather+final) ----
        if (i < 3) {
            const float4* rr4n = (const float4*)(refer_r + (size_t)(b + 1024) * 8192);
            #pragma unroll
            for (int it = 0; it < 8; ++it) rburst[it] = rr4n[tid + it * 256];
        }

        // ---- gather: p[kc..kc+3] += attn[row,kc..] * (e - s*r)[row,kc..] ----
        const int t  = tid >> 5;          // 0..7: row sub-index, also sPart row
        const int kc = (tid & 31) * 4;    // fixed 4 cols per thread
        float p0 = 0.f, p1 = 0.f, p2 = 0.f, p3 = 0.f;

        #pragma unroll
        for (int j = 0; j < 4; ++j) {
            // prefetch second half while consuming first
            int i2 = tid + (j + 4) * 256;
            float4 e2 = re4[i2];
            float4 s2 = se4[i2];

            int row  = j * 8 + t;
            int byte = row * 256 + ((kc * 2) ^ ((row & 7) << 4));
            ushort4 a  = *(const ushort4*)((const char*)sH + byte);
            ushort4 rv = *(const ushort4*)((const char*)sR + byte);
            float4 e = ge[j], s = gs[j];
            p0 += bf2f(a.x) * (e.x - s.x * bf2f(rv.x));
            p1 += bf2f(a.y) * (e.y - s.y * bf2f(rv.y));
            p2 += bf2f(a.z) * (e.z - s.z * bf2f(rv.z));
            p3 += bf2f(a.w) * (e.w - s.w * bf2f(rv.w));
            ge[j] = e2; gs[j] = s2;
        }
        #pragma unroll
        for (int j = 0; j < 4; ++j) {
            int row  = (j + 4) * 8 + t;
            int byte = row * 256 + ((kc * 2) ^ ((row & 7) << 4));
            ushort4 a  = *(const ushort4*)((const char*)sH + byte);
            ushort4 rv = *(const ushort4*)((const char*)sR + byte);
            float4 e = ge[j], s = gs[j];
            p0 += bf2f(a.x) * (e.x - s.x * bf2f(rv.x));
            p1 += bf2f(a.y) * (e.y - s.y * bf2f(rv.y));
            p2 += bf2f(a.z) * (e.z - s.z * bf2f(rv.z));
            p3 += bf2f(a.w) * (e.w - s.w * bf2f(rv.w));
        }
        sPart[t][kc + 0] = p0;
        sPart[t][kc + 1] = p1;
        sPart[t][kc + 2] = p2;
        sPart[t][kc + 3] = p3;
        __syncthreads();   // B5: sR/sH reads done; sPart ready

        // ---- final: row-sum partials, normalize, add query_emb ----
        float fv = 0.f;
        if (tid < 128) {
            #pragma unroll
            for (int r = 0; r < 8; ++r) fv += sPart[r][tid];
            float rn = fabsf(fv), qn = fabsf(qe);
            #pragma unroll
            for (int off = 1; off < 64; off <<= 1) {
                rn += __shfl_xor(rn, off);
                qn += __shfl_xor(qn, off);
            }
            if (lane == 0) { sRed[wv * 2] = rn; sRed[wv * 2 + 1] = qn; }
        }
        __syncthreads();   // B6: sRed ready; also fences sR/sH for next iteration
        if (tid < 128) {
            float RN = sRed[0] + sRed[2];
            float QN = sRed[1] + sRed[3];
            float scale = 1.0f / (1e-9f + (RN / QN) * 2.5f);
            out[(size_t)b * 128 + tid] = qe + fv * scale;
        }
    }
}

extern "C" void kernel_launch(void* const* d_in, const int* in_sizes, int n_in,
                              void* d_out, int out_size, void* d_ws, size_t ws_size,
                              hipStream_t stream) {
    const float* query_emb  = (const float*)d_in[0];
    const float* refer_embs = (const float*)d_in[1];
    const float* query_r    = (const float*)d_in[2];
    const float* refer_r    = (const float*)d_in[3];
    const float* start_embs = (const float*)d_in[4];
    const float* W1         = (const float*)d_in[5];
    const float* b1         = (const float*)d_in[6];
    const float* W2         = (const float*)d_in[7];
    const float* b2         = (const float*)d_in[8];
    float* out = (float*)d_out;

    char* ws = (char*)d_ws;
    float* qv            = (float*)ws;                              // 4096*128*4 = 2 MB
    unsigned short* w1b  = (unsigned short*)(ws + 2 * 1024 * 1024); // 32 KB
    unsigned short* w2b  = w1b + 16384;                             // 32 KB

    pa_prep<<<128, 256, 0, stream>>>(W1, W2, w1b, w2b);
    pa_qv<<<128, 256, 0, stream>>>(query_r, W1, b1, qv);
    pa_main<<<1024, 256, 0, stream>>>(query_emb, refer_embs, refer_r, start_embs,
                                      qv, w1b, w2b, b2, out);
}

// Round 7
// 103.653 us; speedup vs baseline: 1.9303x; 1.9303x over previous
//
#include <hip/hip_runtime.h>
#include <hip/hip_bf16.h>

// ProjectionAggregating: B=4096, N=64, D=128
// out[b,d] = query_emb + final_refer / (1e-9 + ref_norm/query_norm*2.5)
// final_refer[b,d] = sum_n (h1@W2^T + b2)[b,n,d] * (refer_embs - start_embs*refer_r)[b,n,d]
// h1 = relu(query_r@W1a^T + refer_r@W1b^T + b1)   (W1a = W1[:, :128], W1b = W1[:, 128:])

typedef __attribute__((ext_vector_type(8))) short bf16x8;   // 8 bf16 = 4 VGPRs (MFMA A/B frag)
typedef __attribute__((ext_vector_type(4))) float f32x4;    // MFMA C/D frag

// Workgroup barrier WITHOUT the vmcnt(0) drain __syncthreads() emits.
// lgkmcnt(0) retires this thread's ds_writes into LDS (and ds_reads into regs)
// before the barrier, giving full producer->consumer LDS ordering; global
// loads stay in flight across the barrier (compiler still emits vmcnt(N)
// before each dependent register use).
#define WG_BARRIER()                                            \
    do {                                                        \
        asm volatile("s_waitcnt lgkmcnt(0)" ::: "memory");      \
        __builtin_amdgcn_s_barrier();                           \
    } while (0)

__device__ __forceinline__ unsigned short f2bf(float x) {
    unsigned int u = __float_as_uint(x);
    u += 0x7FFFu + ((u >> 16) & 1u);   // round-to-nearest-even
    return (unsigned short)(u >> 16);
}
__device__ __forceinline__ float bf2f(unsigned short h) {
    return __uint_as_float(((unsigned int)h) << 16);
}

// ---- kernel 1: convert W1b (W1[:,128:256]) and W2 to bf16 into workspace ----
__global__ __launch_bounds__(256) void pa_prep(const float* __restrict__ W1,
                                               const float* __restrict__ W2,
                                               unsigned short* __restrict__ w1b,
                                               unsigned short* __restrict__ w2b) {
    int i = blockIdx.x * 256 + threadIdx.x;   // grid covers 32768
    if (i < 16384) {
        int d = i >> 7, k = i & 127;
        w1b[i] = f2bf(W1[d * 256 + 128 + k]);
    } else {
        int j = i - 16384;
        w2b[j] = f2bf(W2[j]);
    }
}

// ---- kernel 2: qv[b,d] = b1[d] + sum_k query_r[b,k] * W1[d,k]  (f32, exact) ----
__global__ __launch_bounds__(256) void pa_qv(const float* __restrict__ query_r,
                                             const float* __restrict__ W1,
                                             const float* __restrict__ b1,
                                             float* __restrict__ qv) {
    __shared__ float wa[128][129];   // W1a, padded (+1) to break bank aliasing
    __shared__ float sq[32][128];    // 32 rows of query_r
    const int tid = threadIdx.x;
    const int b0 = blockIdx.x * 32;  // grid = 128 blocks

    for (int i = tid; i < 128 * 128; i += 256) {
        int d = i >> 7, k = i & 127;
        wa[d][k] = W1[d * 256 + k];
    }
    for (int i = tid; i < 32 * 128; i += 256) {
        sq[i >> 7][i & 127] = query_r[(size_t)b0 * 128 + i];
    }
    __syncthreads();

    const int d = tid & 127;
    const int rb = (tid >> 7) * 16;
    const float bb = b1[d];
    for (int j = 0; j < 16; ++j) {
        int r = rb + j;
        float a0 = 0.f, a1 = 0.f, a2 = 0.f, a3 = 0.f;  // 4-way ILP split
        #pragma unroll
        for (int k = 0; k < 128; k += 4) {
            a0 += sq[r][k + 0] * wa[d][k + 0];
            a1 += sq[r][k + 1] * wa[d][k + 1];
            a2 += sq[r][k + 2] * wa[d][k + 2];
            a3 += sq[r][k + 3] * wa[d][k + 3];
        }
        qv[(size_t)(b0 + r) * 128 + d] = bb + ((a0 + a1) + (a2 + a3));
    }
}

// ---- kernel 3: main fused kernel, one block per b (R4 structure) ----
// Identical phase/barrier layout to the validated R4 kernel; the ONLY change
// is __syncthreads() -> WG_BARRIER() (no vmcnt drain), so global loads issued
// in one phase genuinely stay in flight across barriers (T4 principle).
// 4096 blocks, b = blockIdx.x: dispatch-order locality keeps ~200 MB of the
// working set resident in Infinity Cache across graph replays (R6 lesson).
__global__ __launch_bounds__(256, 2) void pa_main(
    const float* __restrict__ query_emb,
    const float* __restrict__ refer_embs,
    const float* __restrict__ refer_r,
    const float* __restrict__ start_embs,
    const float* __restrict__ qv,
    const unsigned short* __restrict__ w1b,
    const unsigned short* __restrict__ w2b,
    const float* __restrict__ b2,
    float* __restrict__ out) {
    __shared__ __align__(16) unsigned short sR[64 * 128];  // refer_r bf16 swz (16 KB), persists
    __shared__ __align__(16) unsigned short sH[64 * 128];  // h1 bf16 swz -> attn bf16 (16 KB)
    __shared__ float sPart[8][132];                        // col-partials, padded (4.2 KB)
    __shared__ float sQv[128];
    __shared__ float sRed[4];

    const int b    = blockIdx.x;
    const int tid  = threadIdx.x;
    const int lane = tid & 63;
    const int wv   = tid >> 6;       // 4 waves; wave wv owns output cols [32*wv, 32*wv+32)
    const int hl   = lane & 15;
    const int qh   = lane >> 4;      // quarter-wave index
    const int wcol = wv * 32;

    const size_t base = (size_t)b * (64 * 128);
    const float4* rr4 = (const float4*)(refer_r + base);
    const float4* re4 = (const float4*)(refer_embs + base);
    const float4* se4 = (const float4*)(start_embs + base);

    // ---- convoy 1: refer_r burst + small tail data ----
    float4 rburst[8];
    #pragma unroll
    for (int it = 0; it < 8; ++it) rburst[it] = rr4[tid + it * 256];
    float qvv = (tid < 128) ? qv[(size_t)b * 128 + tid] : 0.f;
    float qe  = (tid < 128) ? query_emb[(size_t)b * 128 + tid] : 0.f;
    bf16x8 bW[2][4];
    #pragma unroll
    for (int ct = 0; ct < 2; ++ct)
        #pragma unroll
        for (int ks = 0; ks < 4; ++ks)
            bW[ct][ks] = *(const bf16x8*)(w1b + (wcol + ct * 16 + hl) * 128 + ks * 32 + qh * 8);

    if (tid < 128) sQv[tid] = qvv;
    #pragma unroll
    for (int it = 0; it < 8; ++it) {
        int e0  = (tid + it * 256) * 4;
        int row = e0 >> 7;           // = it*8 + (tid>>5)
        int kc  = e0 & 127;          // = (tid&31)*4
        float4 r = rburst[it];
        ushort4 bv;
        bv.x = f2bf(r.x); bv.y = f2bf(r.y); bv.z = f2bf(r.z); bv.w = f2bf(r.w);
        int byte = row * 256 + ((kc * 2) ^ ((row & 7) << 4));
        *(ushort4*)((char*)sR + byte) = bv;
    }
    WG_BARRIER();   // B1: refer_r staged (lgkm drained; vmem may stay in flight)

    // ---- GEMM1: h1_part[row,col] = sum_k refer_r[row,k] * W1b[col,k] ----
    f32x4 acc1[4][2] = {};
    #pragma unroll
    for (int rt = 0; rt < 4; ++rt) {
        const int row = rt * 16 + hl;
        const int rsw = (row & 7) << 4;
        bf16x8 af[4];
        #pragma unroll
        for (int ks = 0; ks < 4; ++ks) {
            int byte = row * 256 + ((ks * 64 + qh * 16) ^ rsw);
            af[ks] = *(const bf16x8*)((const char*)sR + byte);
        }
        #pragma unroll
        for (int ct = 0; ct < 2; ++ct)
            #pragma unroll
            for (int ks = 0; ks < 4; ++ks)
                acc1[rt][ct] = __builtin_amdgcn_mfma_f32_16x16x32_bf16(af[ks], bW[ct][ks], acc1[rt][ct], 0, 0, 0);
    }

    // ---- epilogue 1: h1 = relu(acc + qv[col]) -> sH ----
    // C/D layout: col = lane&15, row = (lane>>4)*4 + reg
    #pragma unroll
    for (int ct = 0; ct < 2; ++ct) {
        const int col = wcol + ct * 16 + hl;
        const float q = sQv[col];
        #pragma unroll
        for (int rt = 0; rt < 4; ++rt) {
            #pragma unroll
            for (int j = 0; j < 4; ++j) {
                int row = rt * 16 + qh * 4 + j;
                float h = acc1[rt][ct][j] + q;
                h = h > 0.0f ? h : 0.0f;
                int byte = row * 256 + ((col * 2) ^ ((row & 7) << 4));
                *(unsigned short*)((char*)sH + byte) = f2bf(h);
            }
        }
    }
    WG_BARRIER();   // B2: h1 ready

    // ---- GEMM2: attn[row,col] = sum_k h1[row,k] * W2[col,k] ----
    bf16x8 bW2[2][4];
    #pragma unroll
    for (int ct = 0; ct < 2; ++ct)
        #pragma unroll
        for (int ks = 0; ks < 4; ++ks)
            bW2[ct][ks] = *(const bf16x8*)(w2b + (wcol + ct * 16 + hl) * 128 + ks * 32 + qh * 8);

    f32x4 acc2[4][2] = {};
    #pragma unroll
    for (int rt = 0; rt < 4; ++rt) {
        const int row = rt * 16 + hl;
        const int rsw = (row & 7) << 4;
        bf16x8 af[4];
        #pragma unroll
        for (int ks = 0; ks < 4; ++ks) {
            int byte = row * 256 + ((ks * 64 + qh * 16) ^ rsw);
            af[ks] = *(const bf16x8*)((const char*)sH + byte);
        }
        #pragma unroll
        for (int ct = 0; ct < 2; ++ct)
            #pragma unroll
            for (int ks = 0; ks < 4; ++ks)
                acc2[rt][ct] = __builtin_amdgcn_mfma_f32_16x16x32_bf16(af[ks], bW2[ct][ks], acc2[rt][ct], 0, 0, 0);
    }

    // ---- issue first half of e/s stream (flies across B3/B4 now) ----
    float4 ge[4], gs[4];
    #pragma unroll
    for (int j = 0; j < 4; ++j) {
        int idx = tid + j * 256;
        ge[j] = re4[idx];
        gs[j] = se4[idx];
    }
    WG_BARRIER();   // B3: all GEMM2 reads of sH done

    // ---- epilogue 2: attn(+b2) -> sH (same swizzle) ----
    #pragma unroll
    for (int ct = 0; ct < 2; ++ct) {
        const int col = wcol + ct * 16 + hl;
        const float bb = b2[col];
        #pragma unroll
        for (int rt = 0; rt < 4; ++rt) {
            #pragma unroll
            for (int j = 0; j < 4; ++j) {
                int row = rt * 16 + qh * 4 + j;
                int byte = row * 256 + ((col * 2) ^ ((row & 7) << 4));
                *(unsigned short*)((char*)sH + byte) = f2bf(acc2[rt][ct][j] + bb);
            }
        }
    }
    WG_BARRIER();   // B4: attn ready

    // ---- gather: p[kc..kc+3] += attn[row,kc..] * (e - s*r)[row,kc..] ----
    const int t  = tid >> 5;          // 0..7: row sub-index, also sPart row
    const int kc = (tid & 31) * 4;    // fixed 4 cols per thread
    float p0 = 0.f, p1 = 0.f, p2 = 0.f, p3 = 0.f;

    #pragma unroll
    for (int j = 0; j < 4; ++j) {
        // prefetch second half while consuming first
        int i2 = tid + (j + 4) * 256;
        float4 e2 = re4[i2];
        float4 s2 = se4[i2];

        int row  = j * 8 + t;
        int byte = row * 256 + ((kc * 2) ^ ((row & 7) << 4));
        ushort4 a  = *(const ushort4*)((const char*)sH + byte);
        ushort4 rv = *(const ushort4*)((const char*)sR + byte);
        float4 e = ge[j], s = gs[j];
        p0 += bf2f(a.x) * (e.x - s.x * bf2f(rv.x));
        p1 += bf2f(a.y) * (e.y - s.y * bf2f(rv.y));
        p2 += bf2f(a.z) * (e.z - s.z * bf2f(rv.z));
        p3 += bf2f(a.w) * (e.w - s.w * bf2f(rv.w));
        ge[j] = e2; gs[j] = s2;
    }
    #pragma unroll
    for (int j = 0; j < 4; ++j) {
        int row  = (j + 4) * 8 + t;
        int byte = row * 256 + ((kc * 2) ^ ((row & 7) << 4));
        ushort4 a  = *(const ushort4*)((const char*)sH + byte);
        ushort4 rv = *(const ushort4*)((const char*)sR + byte);
        float4 e = ge[j], s = gs[j];
        p0 += bf2f(a.x) * (e.x - s.x * bf2f(rv.x));
        p1 += bf2f(a.y) * (e.y - s.y * bf2f(rv.y));
        p2 += bf2f(a.z) * (e.z - s.z * bf2f(rv.z));
        p3 += bf2f(a.w) * (e.w - s.w * bf2f(rv.w));
    }
    sPart[t][kc + 0] = p0;
    sPart[t][kc + 1] = p1;
    sPart[t][kc + 2] = p2;
    sPart[t][kc + 3] = p3;
    WG_BARRIER();   // B5: sR/sH reads done; sPart ready

    // ---- final: row-sum partials, normalize, add query_emb (preloaded) ----
    float fv = 0.f;
    if (tid < 128) {
        #pragma unroll
        for (int r = 0; r < 8; ++r) fv += sPart[r][tid];
        float rn = fabsf(fv), qn = fabsf(qe);
        #pragma unroll
        for (int off = 1; off < 64; off <<= 1) {
            rn += __shfl_xor(rn, off);
            qn += __shfl_xor(qn, off);
        }
        if (lane == 0) { sRed[wv * 2] = rn; sRed[wv * 2 + 1] = qn; }
    }
    WG_BARRIER();   // B6: sRed ready
    if (tid < 128) {
        float RN = sRed[0] + sRed[2];
        float QN = sRed[1] + sRed[3];
        float scale = 1.0f / (1e-9f + (RN / QN) * 2.5f);
        out[(size_t)b * 128 + tid] = qe + fv * scale;
    }
}

extern "C" void kernel_launch(void* const* d_in, const int* in_sizes, int n_in,
                              void* d_out, int out_size, void* d_ws, size_t ws_size,
                              hipStream_t stream) {
    const float* query_emb  = (const float*)d_in[0];
    const float* refer_embs = (const float*)d_in[1];
    const float* query_r    = (const float*)d_in[2];
    const float* refer_r    = (const float*)d_in[3];
    const float* start_embs = (const float*)d_in[4];
    const float* W1         = (const float*)d_in[5];
    const float* b1         = (const float*)d_in[6];
    const float* W2         = (const float*)d_in[7];
    const float* b2         = (const float*)d_in[8];
    float* out = (float*)d_out;

    char* ws = (char*)d_ws;
    float* qv            = (float*)ws;                              // 4096*128*4 = 2 MB
    unsigned short* w1b  = (unsigned short*)(ws + 2 * 1024 * 1024); // 32 KB
    unsigned short* w2b  = w1b + 16384;                             // 32 KB

    pa_prep<<<128, 256, 0, stream>>>(W1, W2, w1b, w2b);
    pa_qv<<<128, 256, 0, stream>>>(query_r, W1, b1, qv);
    pa_main<<<4096, 256, 0, stream>>>(query_emb, refer_embs, refer_r, start_embs,
                                      qv, w1b, w2b, b2, out);
}